// Round 4
// baseline (190.953 us; speedup 1.0000x reference)
//
#include <hip/hip_runtime.h>
#include <math.h>

#define BB 256
#define DD 5120
#define NN 16
#define RR 160
#define CT 192          // 160 (t) + 16 (Bm) + 16 (Cm)
#define NSPLIT 64
#define KSPL 80         // K per split: 5120/64
#define TMP_ELEMS (BB * CT)          // 49152

// ---------------- K1: partials[s][b][c] = x[b, ks:ks+80] @ Wcat[ks:ks+80, c]
// grid: (3 c-tiles, 4 b-tiles, 64 k-splits) = 768 blocks, block 256, micro 4x4
__global__ __launch_bounds__(256) void k1_gemm(const float* __restrict__ x,
                                               const float* __restrict__ Wxdt,
                                               const float* __restrict__ Wbc,
                                               float* __restrict__ part) {
    __shared__ float xs[16][68];   // [k][b] transposed
    __shared__ float ws[16][64];   // [k][c]
    const int tid = threadIdx.x;
    const int tx = tid & 15, ty = tid >> 4;
    const int c0 = blockIdx.x * 64;
    const int b0 = blockIdx.y * 64;
    const int k0 = blockIdx.z * KSPL;
    float acc[4][4] = {};

    for (int kc = 0; kc < KSPL; kc += 16) {
        // stage x tile transposed: 64 b x 16 k = 256 float4, 1/thread
        {
            const int row = tid >> 2;        // 0..63
            const int j4  = (tid & 3) * 4;   // 0,4,8,12
            const float4 v = *(const float4*)&x[(size_t)(b0 + row) * DD + k0 + kc + j4];
            xs[j4 + 0][row] = v.x;
            xs[j4 + 1][row] = v.y;
            xs[j4 + 2][row] = v.z;
            xs[j4 + 3][row] = v.w;
        }
        // stage W tile: 16 k x 64 c = 256 float4, 1/thread
        {
            const int r  = tid >> 4;         // 0..15
            const int c4 = (tid & 15) * 4;
            const int kg = k0 + kc + r;
            const int cg = c0 + c4;
            float4 v;
            if (cg < RR) v = *(const float4*)&Wxdt[(size_t)kg * RR + cg];
            else         v = *(const float4*)&Wbc[(size_t)kg * 32 + (cg - RR)];
            *(float4*)&ws[r][c4] = v;
        }
        __syncthreads();
        #pragma unroll
        for (int k = 0; k < 16; ++k) {
            const float4 a4 = *(const float4*)&xs[k][ty * 4];
            const float4 w4 = *(const float4*)&ws[k][tx * 4];
            const float av[4] = {a4.x, a4.y, a4.z, a4.w};
            const float wv[4] = {w4.x, w4.y, w4.z, w4.w};
            #pragma unroll
            for (int u = 0; u < 4; ++u)
                #pragma unroll
                for (int v = 0; v < 4; ++v)
                    acc[u][v] = fmaf(av[u], wv[v], acc[u][v]);
        }
        __syncthreads();
    }

    float* p = part + (size_t)blockIdx.z * TMP_ELEMS;
    #pragma unroll
    for (int u = 0; u < 4; ++u) {
        const int b = b0 + ty * 4 + u;
        *(float4*)&p[b * CT + c0 + tx * 4] =
            make_float4(acc[u][0], acc[u][1], acc[u][2], acc[u][3]);
    }
}

// ---------------- K_RED: tmp = sum_s partials --------------------------------
// grid: 192 blocks x 256
__global__ __launch_bounds__(256) void k_red(const float* __restrict__ part,
                                             float* __restrict__ tmp) {
    const int idx = blockIdx.x * 256 + threadIdx.x;
    float s = 0.f;
    #pragma unroll
    for (int z = 0; z < NSPLIT; ++z) s += part[(size_t)z * TMP_ELEMS + idx];
    tmp[idx] = s;
}

// ---------------- K23: sync-free GEMV dt + fused SSM stream ------------------
// grid: (10 d-chunks of 512, 64 b-groups of 4), block 256.
// Thread owns d2 = d0 + 2*tid (+1) and all 4 b's of the group.
__global__ __launch_bounds__(256) void k23_fused(const float* __restrict__ x,
                                                 const float* __restrict__ h0,
                                                 const float* __restrict__ Wdt,
                                                 const float* __restrict__ bdt,
                                                 const float* __restrict__ Alog,
                                                 const float* __restrict__ tmp,
                                                 float* __restrict__ out) {
    __shared__ float4 ts4[RR];      // ts4[r] = { t[b0+0][r], .., t[b0+3][r] }
    __shared__ float  BCs[4][32];   // per-b: Bm [0..15], Cm [16..31]
    const int tid = threadIdx.x;
    const int d0  = blockIdx.x * 512;
    const int b0  = blockIdx.y * 4;
    const int d2  = d0 + tid * 2;

    // ---- stage t (transposed across the 4 b's) and Bm/Cm ----
    if (tid < RR) {
        float4 t;
        t.x = tmp[(size_t)(b0 + 0) * CT + tid];
        t.y = tmp[(size_t)(b0 + 1) * CT + tid];
        t.z = tmp[(size_t)(b0 + 2) * CT + tid];
        t.w = tmp[(size_t)(b0 + 3) * CT + tid];
        ts4[tid] = t;
    } else if (tid < RR + 32) {
        const int idx = tid - RR;
        const int j  = idx >> 3;
        const int c4 = (idx & 7) * 4;
        const float4 v = *(const float4*)&tmp[(size_t)(b0 + j) * CT + RR + c4];
        BCs[j][c4 + 0] = v.x; BCs[j][c4 + 1] = v.y;
        BCs[j][c4 + 2] = v.z; BCs[j][c4 + 3] = v.w;
    }

    // ---- negA = -exp(A_log) for this thread's two d's (registers) ----
    float na0[NN], na1[NN];
    #pragma unroll
    for (int q4 = 0; q4 < 4; ++q4) {
        const float4 a = *(const float4*)&Alog[(size_t)d2 * NN + q4 * 4];
        na0[q4 * 4 + 0] = -__expf(a.x); na0[q4 * 4 + 1] = -__expf(a.y);
        na0[q4 * 4 + 2] = -__expf(a.z); na0[q4 * 4 + 3] = -__expf(a.w);
        const float4 c = *(const float4*)&Alog[(size_t)(d2 + 1) * NN + q4 * 4];
        na1[q4 * 4 + 0] = -__expf(c.x); na1[q4 * 4 + 1] = -__expf(c.y);
        na1[q4 * 4 + 2] = -__expf(c.z); na1[q4 * 4 + 3] = -__expf(c.w);
    }
    __syncthreads();   // the only barrier

    // ---- GEMV: acc[j][i] = sum_r t[b0+j][r] * Wdt[r][d2+i] ----
    float acc[4][2] = {};
    #pragma unroll 8
    for (int r = 0; r < RR; ++r) {
        const float2 w = *(const float2*)&Wdt[(size_t)r * DD + d2];
        const float4 tv = ts4[r];
        acc[0][0] = fmaf(tv.x, w.x, acc[0][0]); acc[0][1] = fmaf(tv.x, w.y, acc[0][1]);
        acc[1][0] = fmaf(tv.y, w.x, acc[1][0]); acc[1][1] = fmaf(tv.y, w.y, acc[1][1]);
        acc[2][0] = fmaf(tv.z, w.x, acc[2][0]); acc[2][1] = fmaf(tv.z, w.y, acc[2][1]);
        acc[3][0] = fmaf(tv.w, w.x, acc[3][0]); acc[3][1] = fmaf(tv.w, w.y, acc[3][1]);
    }

    const float2 bb = *(const float2*)&bdt[d2];

    // ---- SSM epilogue per b ----
    #pragma unroll
    for (int j = 0; j < 4; ++j) {
        const int b = b0 + j;
        const size_t base = (size_t)b * DD + d2;

        const float z0  = acc[j][0] + bb.x;
        const float dt0 = fmaxf(z0, 0.f) + log1pf(__expf(-fabsf(z0)));
        const float z1  = acc[j][1] + bb.y;
        const float dt1 = fmaxf(z1, 0.f) + log1pf(__expf(-fabsf(z1)));

        const float2 xe = *(const float2*)&x[base];
        const float dtx0 = dt0 * xe.x;
        const float dtx1 = dt1 * xe.y;

        // h0 for both d's: 128 B contiguous, 8 float4 loads issued together
        const float* hp = &h0[base * NN];
        float4 ha[4], hb[4];
        #pragma unroll
        for (int i = 0; i < 4; ++i) ha[i] = *(const float4*)&hp[i * 4];
        #pragma unroll
        for (int i = 0; i < 4; ++i) hb[i] = *(const float4*)&hp[NN + i * 4];

        // Bm/Cm into registers (broadcast b128 reads)
        float bm[NN], cm[NN];
        #pragma unroll
        for (int q4 = 0; q4 < 4; ++q4) {
            const float4 v = *(const float4*)&BCs[j][q4 * 4];
            bm[q4 * 4 + 0] = v.x; bm[q4 * 4 + 1] = v.y;
            bm[q4 * 4 + 2] = v.z; bm[q4 * 4 + 3] = v.w;
            const float4 w = *(const float4*)&BCs[j][16 + q4 * 4];
            cm[q4 * 4 + 0] = w.x; cm[q4 * 4 + 1] = w.y;
            cm[q4 * 4 + 2] = w.z; cm[q4 * 4 + 3] = w.w;
        }

        float y0a = xe.x, y0b = 0.f, y1a = xe.y, y1b = 0.f;
        #pragma unroll
        for (int q4 = 0; q4 < 4; ++q4) {
            const float hv0[4] = {ha[q4].x, ha[q4].y, ha[q4].z, ha[q4].w};
            const float hv1[4] = {hb[q4].x, hb[q4].y, hb[q4].z, hb[q4].w};
            #pragma unroll
            for (int q = 0; q < 4; ++q) {
                const int n = q4 * 4 + q;
                const float dA0 = __expf(na0[n] * dt0);
                const float h00 = fmaf(dA0, hv0[q], dtx0 * bm[n]);
                const float dA1 = __expf(na1[n] * dt1);
                const float h11 = fmaf(dA1, hv1[q], dtx1 * bm[n]);
                if (n & 1) { y0b = fmaf(h00, cm[n], y0b); y1b = fmaf(h11, cm[n], y1b); }
                else       { y0a = fmaf(h00, cm[n], y0a); y1a = fmaf(h11, cm[n], y1a); }
            }
        }
        *(float2*)&out[base] = make_float2(y0a + y0b, y1a + y1b);
    }
}

extern "C" void kernel_launch(void* const* d_in, const int* in_sizes, int n_in,
                              void* d_out, int out_size, void* d_ws, size_t ws_size,
                              hipStream_t stream) {
    const float* x    = (const float*)d_in[0];
    const float* h0   = (const float*)d_in[1];
    const float* Wxdt = (const float*)d_in[2];
    const float* Wdt  = (const float*)d_in[3];
    const float* bdt  = (const float*)d_in[4];
    const float* Wbc  = (const float*)d_in[5];
    const float* Alog = (const float*)d_in[6];
    float* out = (float*)d_out;

    // ws layout (floats): partials[64*49152] | tmp[49152]
    float* part = (float*)d_ws;
    float* tmp  = part + (size_t)NSPLIT * TMP_ELEMS;

    k1_gemm<<<dim3(3, 4, NSPLIT), 256, 0, stream>>>(x, Wxdt, Wbc, part);
    k_red<<<dim3(TMP_ELEMS / 256), 256, 0, stream>>>(part, tmp);
    k23_fused<<<dim3(10, 64), 256, 0, stream>>>(x, h0, Wdt, bdt, Alog, tmp, out);
}